// Round 3
// baseline (1233.148 us; speedup 1.0000x reference)
//
#include <hip/hip_runtime.h>
#include <hip/hip_bf16.h>

#define LL 12
#define BB 32
#define SS 197
#define DV 768
#define DD 512
#define CC 48
#define VV 49
#define LOSS_DEN 786432.0f

typedef unsigned short u16;
typedef unsigned int u32;
using bf16x8 = __attribute__((ext_vector_type(8))) __bf16;
using f32x4 = __attribute__((ext_vector_type(4))) float;

__device__ __forceinline__ u16 bf16h(float x) {
    u32 u = __builtin_bit_cast(u32, x);
    return (u16)((u + 0x7FFFu + ((u >> 16) & 1u)) >> 16);
}
__device__ __forceinline__ float bf2f(u16 h) {
    u32 u = ((u32)h) << 16;
    return __builtin_bit_cast(float, u);
}
__device__ __forceinline__ f32x4 mfma16(bf16x8 a, bf16x8 b, f32x4 c) {
    return __builtin_amdgcn_mfma_f32_16x16x32_bf16(a, b, c, 0, 0, 0);
}
__device__ __forceinline__ void gl_lds16(const void* g, void* s) {
    __builtin_amdgcn_global_load_lds((const __attribute__((address_space(1))) u32*)g,
                                     (__attribute__((address_space(3))) u32*)s, 16, 0, 0);
}

// ---------------------------------------------------------------------------
// Pool + bf16 hi/lo split of X
__global__ __launch_bounds__(256) void pool_split(const float* __restrict__ feats,
                                                  u16* __restrict__ Xh, u16* __restrict__ Xl) {
    int row = blockIdx.x;
    int t = threadIdx.x;
    int v = row % VV;
    int lb = row / VV;
    const float* f = feats + (size_t)lb * SS * DV;
    for (int d = t; d < DV; d += 256) {
        float val;
        if (v == 0) {
            val = f[d];
        } else {
            int i = v - 1;
            int s = (i * 196) / 48;
            int e = ((i + 1) * 196 + 47) / 48;
            float acc = 0.0f;
            for (int j = s; j < e; ++j) acc += f[(size_t)(1 + j) * DV + d];
            val = acc / (float)(e - s);
        }
        u16 h = bf16h(val);
        Xh[(size_t)row * DV + d] = h;
        Xl[(size_t)row * DV + d] = bf16h(val - bf2f(h));
    }
}

// Combined weight splits (W_lin, W_gate, W_upd)
#define NL (512 * 768)
#define NG (512 * 1536)
#define NU (512 * 1024)
__global__ __launch_bounds__(256) void wsplit_all(const float* __restrict__ Wl,
                                                  const float* __restrict__ Wg,
                                                  const float* __restrict__ Wu,
                                                  u16* Wlh, u16* Wll, u16* Wgh, u16* Wgl,
                                                  u16* Wuh, u16* Wul) {
    int i = blockIdx.x * 256 + threadIdx.x;
    float v;
    u16 *ph, *pl;
    int j;
    if (i < NL) { v = Wl[i]; ph = Wlh; pl = Wll; j = i; }
    else if (i < NL + NG) { j = i - NL; v = Wg[j]; ph = Wgh; pl = Wgl; }
    else { j = i - NL - NG; v = Wu[j]; ph = Wuh; pl = Wul; }
    u16 hh = bf16h(v);
    ph[j] = hh;
    pl[j] = bf16h(v - bf2f(hh));
}

// ---------------------------------------------------------------------------
// f32 GEMM for ctx projection, with optional bf16 plane epilogue.
__global__ __launch_bounds__(256) void gemm_nt(const float* __restrict__ A, int lda,
                                               const float* __restrict__ W, int K,
                                               const float* __restrict__ bias,
                                               float* __restrict__ Cout,
                                               u16* __restrict__ Ch, u16* __restrict__ Cl) {
    __shared__ float As[32][65];
    __shared__ float Bs[32][65];
    int t = threadIdx.x;
    int m0 = blockIdx.x * 64;
    int n0 = blockIdx.y * 64;
    int r = t >> 2;
    int kc = (t & 3) * 8;
    int tx = t & 15, ty = t >> 4;
    float acc[4][4] = {};
    for (int k0 = 0; k0 < K; k0 += 32) {
        const float4* pa = (const float4*)(A + (size_t)(m0 + r) * lda + k0 + kc);
        float4 a0 = pa[0], a1 = pa[1];
        const float4* pw = (const float4*)(W + (size_t)(n0 + r) * K + k0 + kc);
        float4 w0 = pw[0], w1 = pw[1];
        As[kc + 0][r] = a0.x; As[kc + 1][r] = a0.y; As[kc + 2][r] = a0.z; As[kc + 3][r] = a0.w;
        As[kc + 4][r] = a1.x; As[kc + 5][r] = a1.y; As[kc + 6][r] = a1.z; As[kc + 7][r] = a1.w;
        Bs[kc + 0][r] = w0.x; Bs[kc + 1][r] = w0.y; Bs[kc + 2][r] = w0.z; Bs[kc + 3][r] = w0.w;
        Bs[kc + 4][r] = w1.x; Bs[kc + 5][r] = w1.y; Bs[kc + 6][r] = w1.z; Bs[kc + 7][r] = w1.w;
        __syncthreads();
#pragma unroll
        for (int kk = 0; kk < 32; ++kk) {
            float a[4], b[4];
#pragma unroll
            for (int i = 0; i < 4; ++i) { a[i] = As[kk][ty * 4 + i]; b[i] = Bs[kk][tx * 4 + i]; }
#pragma unroll
            for (int i = 0; i < 4; ++i)
#pragma unroll
                for (int j = 0; j < 4; ++j) acc[i][j] += a[i] * b[j];
        }
        __syncthreads();
    }
#pragma unroll
    for (int i = 0; i < 4; ++i) {
        int m = m0 + ty * 4 + i;
#pragma unroll
        for (int j = 0; j < 4; ++j) {
            int n = n0 + tx * 4 + j;
            float v = acc[i][j] + (bias ? bias[n] : 0.0f);
            size_t o = (size_t)m * DD + n;
            Cout[o] = v;
            if (Ch) {
                u16 hh = bf16h(v);
                Ch[o] = hh;
                Cl[o] = bf16h(v - bf2f(hh));
            }
        }
    }
}

// ---------------------------------------------------------------------------
// vt = X @ W_lin.T + b_lin  (bf16x3 MFMA), emits bf16 hi/lo planes.
__global__ __launch_bounds__(256, 2) void vt_gemm(const u16* __restrict__ Xh, const u16* __restrict__ Xl,
                                                  const u16* __restrict__ Wh, const u16* __restrict__ Wl,
                                                  const float* __restrict__ bias,
                                                  u16* __restrict__ vthp, u16* __restrict__ vtlp) {
    __shared__ u16 sm[24576];
    int tid = threadIdx.x;
    int w = tid >> 6, l = tid & 63, lr = l & 15, ls = l >> 4;
    int m0 = blockIdx.x * 128, n0 = blockIdx.y * 64;
    f32x4 acc[2][4];
#pragma unroll
    for (int i = 0; i < 2; ++i)
#pragma unroll
        for (int j = 0; j < 4; ++j) acc[i][j] = f32x4{0.f, 0.f, 0.f, 0.f};

    auto stage = [&](u16* dst, int k0) {
#pragma unroll
        for (int is = 0; is < 6; ++is) {
            int q = is * 256 + tid;
            const u16* src;
            int off;
            if (is < 2)      { int qr = q;        int row = qr >> 2, sl = qr & 3; src = Xh + (size_t)(m0 + row) * DV + k0 + ((sl ^ ((row >> 1) & 3)) << 3); off = qr * 8; }
            else if (is < 4) { int qr = q - 512;  int row = qr >> 2, sl = qr & 3; src = Xl + (size_t)(m0 + row) * DV + k0 + ((sl ^ ((row >> 1) & 3)) << 3); off = 4096 + qr * 8; }
            else if (is < 5) { int qr = q - 1024; int row = qr >> 2, sl = qr & 3; src = Wh + (size_t)(n0 + row) * DV + k0 + ((sl ^ ((row >> 1) & 3)) << 3); off = 8192 + qr * 8; }
            else             { int qr = q - 1280; int row = qr >> 2, sl = qr & 3; src = Wl + (size_t)(n0 + row) * DV + k0 + ((sl ^ ((row >> 1) & 3)) << 3); off = 10240 + qr * 8; }
            gl_lds16(src, dst + off);
        }
    };

    stage(sm, 0);
    __syncthreads();
    for (int t = 0; t < 24; ++t) {
        u16* cur = sm + ((t & 1) ? 12288 : 0);
        u16* nxt = sm + ((t & 1) ? 0 : 12288);
        if (t + 1 < 24) stage(nxt, (t + 1) * 32);
        bf16x8 ah[2], al2[2], bh[4], bl2[4];
#pragma unroll
        for (int rf = 0; rf < 2; ++rf) {
            int row = 32 * w + 16 * rf + lr;
            int ro = row * 32 + ((ls ^ ((row >> 1) & 3)) << 3);
            ah[rf] = *(const bf16x8*)(cur + ro);
            al2[rf] = *(const bf16x8*)(cur + 4096 + ro);
        }
#pragma unroll
        for (int cf = 0; cf < 4; ++cf) {
            int n = 16 * cf + lr;
            int no = n * 32 + ((ls ^ ((n >> 1) & 3)) << 3);
            bh[cf] = *(const bf16x8*)(cur + 8192 + no);
            bl2[cf] = *(const bf16x8*)(cur + 10240 + no);
        }
#pragma unroll
        for (int rf = 0; rf < 2; ++rf)
#pragma unroll
            for (int cf = 0; cf < 4; ++cf) {
                acc[rf][cf] = mfma16(ah[rf], bh[cf], acc[rf][cf]);
                acc[rf][cf] = mfma16(ah[rf], bl2[cf], acc[rf][cf]);
                acc[rf][cf] = mfma16(al2[rf], bh[cf], acc[rf][cf]);
            }
        __syncthreads();
    }
#pragma unroll
    for (int rf = 0; rf < 2; ++rf)
#pragma unroll
        for (int cf = 0; cf < 4; ++cf)
#pragma unroll
            for (int r = 0; r < 4; ++r) {
                int row = m0 + 32 * w + 16 * rf + 4 * ls + r;
                int col = n0 + 16 * cf + lr;
                float v = acc[rf][cf][r] + bias[col];
                size_t o = (size_t)row * DD + col;
                u16 hh = bf16h(v);
                vthp[o] = hh;
                vtlp[o] = bf16h(v - bf2f(hh));
            }
}

// ---------------------------------------------------------------------------
// Transpose vt planes per (l,b): [49][512] -> [512][64] (v>=49 zero-padded)
__global__ __launch_bounds__(256) void vtT_kernel(const u16* __restrict__ vth, const u16* __restrict__ vtl,
                                                  u16* __restrict__ vtTh, u16* __restrict__ vtTl) {
    __shared__ u16 tile[49 * 520];
    int lb = blockIdx.x;
    int tid = threadIdx.x;
    for (int pl = 0; pl < 2; ++pl) {
        const u16* src = (pl ? vtl : vth) + (size_t)lb * VV * DD;
        u16* dst = (pl ? vtTl : vtTh) + (size_t)lb * 512 * 64;
        for (int q = tid; q < VV * 64; q += 256) {
            int r = q >> 6, c = q & 63;
            *(uint4*)(tile + r * 520 + c * 8) = *(const uint4*)(src + (size_t)r * DD + c * 8);
        }
        __syncthreads();
        for (int q = tid; q < 512 * 64; q += 256) {
            int d = q >> 6, v = q & 63;
            dst[q] = (v < VV) ? tile[v * 520 + d] : (u16)0;
        }
        __syncthreads();
    }
}

// ---------------------------------------------------------------------------
// MFMA attention: one block per image b (8 waves). S = q·vt^T (x3), softmax, fuse = P·vt (x3).
__global__ __launch_bounds__(512) void attn_mfma(const u16* __restrict__ qh, const u16* __restrict__ ql,
                                                 const u16* __restrict__ vth, const u16* __restrict__ vtl,
                                                 const u16* __restrict__ vtTh, const u16* __restrict__ vtTl,
                                                 float* __restrict__ fuse_out,
                                                 u16* __restrict__ fh, u16* __restrict__ fl,
                                                 const float* __restrict__ fuse_prev,
                                                 float* __restrict__ loss_acc, int do_loss) {
    __shared__ char smc[59712];
    u16* QST = (u16*)smc;                   // QK q stage: [db][pl][1536]
    u16* VST = (u16*)(smc + 12288);         // QK vt stage: [db][pl][2048]
    u16* VTT = (u16*)smc;                   // PV Vt stage: 16384 u16 (reuses QK region)
    float* Sb = (float*)(smc + 32768);      // [48][68]
    u16* Ph = (u16*)(smc + 45824);          // [48][72]
    u16* Pl = (u16*)(smc + 52736);          // [48][72]
    float* red = (float*)(smc + 59648);     // [8]

    int b = blockIdx.x;
    int tid = threadIdx.x;
    int w = tid >> 6, l = tid & 63, lr = l & 15, ls = l >> 4;
    int qrow0 = b * CC;
    size_t vtrow0 = (size_t)b * VV * DD;

    auto stageQK = [&](int db, int k0) {
        if (tid < 192) {
            int row = tid >> 2, slot = tid & 3;
            size_t g = (size_t)(qrow0 + row) * DD + k0 + slot * 8;
            gl_lds16(qh + g, QST + db * 3072 + tid * 8);
            gl_lds16(ql + g, QST + db * 3072 + 1536 + tid * 8);
        } else if (tid >= 256) {
            int t2 = tid - 256;
            int row = t2 >> 2, slot = t2 & 3;
            size_t g = vtrow0 + (size_t)row * DD + k0 + slot * 8;
            gl_lds16(vth + g, VST + db * 4096 + t2 * 8);
            gl_lds16(vtl + g, VST + db * 4096 + 2048 + t2 * 8);
        }
    };
    auto stageVt = [&](const u16* base, int v0) {
#pragma unroll
        for (int i = 0; i < 4; ++i) {
            int idx = i * 512 + tid;
            int d = idx >> 2, slot = idx & 3;
            gl_lds16(base + (size_t)b * 32768 + d * 64 + v0 + slot * 8, VTT + idx * 8);
        }
    };

    // ---- QK^T ----
    int c4 = w & 3, wh = w >> 2;
    f32x4 acc_s[3];
#pragma unroll
    for (int i = 0; i < 3; ++i) acc_s[i] = f32x4{0.f, 0.f, 0.f, 0.f};
    stageQK(0, 0);
    __syncthreads();
    for (int t = 0; t < 16; ++t) {
        int cur = t & 1;
        if (t + 1 < 16) stageQK(cur ^ 1, (t + 1) * 32);
        const u16* qt = QST + cur * 3072;
        const u16* vtt = VST + cur * 4096;
        int bidx = (16 * c4 + lr) * 32 + ls * 8;
        bf16x8 vh = *(const bf16x8*)(vtt + bidx);
        bf16x8 vl = *(const bf16x8*)(vtt + 2048 + bidx);
        int rlo = wh ? 2 : 0, rhi = wh ? 3 : 2;
        for (int rf = rlo; rf < rhi; ++rf) {
            int aidx = (16 * rf + lr) * 32 + ls * 8;
            bf16x8 qhv = *(const bf16x8*)(qt + aidx);
            bf16x8 qlv = *(const bf16x8*)(qt + 1536 + aidx);
            acc_s[rf] = mfma16(qhv, vh, acc_s[rf]);
            acc_s[rf] = mfma16(qhv, vl, acc_s[rf]);
            acc_s[rf] = mfma16(qlv, vh, acc_s[rf]);
        }
        __syncthreads();
    }
    // write S
    {
        int rlo = wh ? 2 : 0, rhi = wh ? 3 : 2;
        for (int rf = rlo; rf < rhi; ++rf)
#pragma unroll
            for (int r = 0; r < 4; ++r)
                Sb[(16 * rf + 4 * ls + r) * 68 + 16 * c4 + lr] = acc_s[rf][r];
    }
    stageVt(vtTh, 0);  // prefetch V-hi for first PV step
    __syncthreads();

    // ---- softmax -> P planes ----
    if (tid < 192) {
        int row = tid >> 2, sub = tid & 3;
        float mx = -1e30f;
        for (int c = sub; c < VV; c += 4) mx = fmaxf(mx, Sb[row * 68 + c]);
        mx = fmaxf(mx, __shfl_xor(mx, 1));
        mx = fmaxf(mx, __shfl_xor(mx, 2));
        float s = 0.0f;
        for (int c = sub; c < VV; c += 4) {
            float e = __expf(Sb[row * 68 + c] - mx);
            Sb[row * 68 + c] = e;
            s += e;
        }
        s += __shfl_xor(s, 1);
        s += __shfl_xor(s, 2);
        float inv = 1.0f / s;
        for (int c = sub; c < 64; c += 4) {
            u16 hh = 0, ll2 = 0;
            if (c < VV) {
                float p = Sb[row * 68 + c] * inv;
                hh = bf16h(p);
                ll2 = bf16h(p - bf2f(hh));
            }
            Ph[row * 72 + c] = hh;
            Pl[row * 72 + c] = ll2;
        }
    }
    __syncthreads();

    // ---- PV ----
    f32x4 acc_f[3][4];
#pragma unroll
    for (int i = 0; i < 3; ++i)
#pragma unroll
        for (int j = 0; j < 4; ++j) acc_f[i][j] = f32x4{0.f, 0.f, 0.f, 0.f};

    auto pvPass = [&](const u16* Pp, int v0) {
        bf16x8 av[3];
#pragma unroll
        for (int rf = 0; rf < 3; ++rf)
            av[rf] = *(const bf16x8*)(Pp + (16 * rf + lr) * 72 + v0 + ls * 8);
#pragma unroll
        for (int cf = 0; cf < 4; ++cf) {
            int n = (w << 6) + (cf << 4) + lr;
            bf16x8 bv = *(const bf16x8*)(VTT + n * 32 + ls * 8);
#pragma unroll
            for (int rf = 0; rf < 3; ++rf) acc_f[rf][cf] = mfma16(av[rf], bv, acc_f[rf][cf]);
        }
    };

    // ks = 0: Vh already staged
    pvPass(Ph, 0); pvPass(Pl, 0);
    __syncthreads();
    stageVt(vtTl, 0);
    __syncthreads();
    pvPass(Ph, 0);
    __syncthreads();
    stageVt(vtTh, 32);
    __syncthreads();
    pvPass(Ph, 32); pvPass(Pl, 32);
    __syncthreads();
    stageVt(vtTl, 32);
    __syncthreads();
    pvPass(Ph, 32);

    // ---- epilogue: write fuse (+planes), loss ----
    float d2 = 0.0f;
#pragma unroll
    for (int rf = 0; rf < 3; ++rf)
#pragma unroll
        for (int cf = 0; cf < 4; ++cf)
#pragma unroll
            for (int r = 0; r < 4; ++r) {
                int row = 16 * rf + 4 * ls + r;
                int col = (w << 6) + (cf << 4) + lr;
                float f = acc_f[rf][cf][r];
                size_t o = (size_t)(qrow0 + row) * DD + col;
                fuse_out[o] = f;
                u16 hh = bf16h(f);
                fh[o] = hh;
                fl[o] = bf16h(f - bf2f(hh));
                if (do_loss) {
                    float d = f - fuse_prev[o];
                    d2 += d * d;
                }
            }
    if (do_loss) {
#pragma unroll
        for (int off = 32; off > 0; off >>= 1) d2 += __shfl_xor(d2, off);
        if (l == 0) red[w] = d2;
        __syncthreads();
        if (tid == 0) {
            float s = 0.0f;
#pragma unroll
            for (int i = 0; i < 8; ++i) s += red[i];
            atomicAdd(loss_acc, s);
        }
    }
}

// ---------------------------------------------------------------------------
// gate/upd fused bf16x3 MFMA, 2x2 wave layout.
__global__ __launch_bounds__(256, 2) void gate_upd2(
    const u16* __restrict__ fhp, const u16* __restrict__ flp,
    const u16* __restrict__ qhp, const u16* __restrict__ qlp,
    const u16* __restrict__ chp, const u16* __restrict__ clp,
    const u16* __restrict__ Wgh, const u16* __restrict__ Wgl,
    const u16* __restrict__ Wuh, const u16* __restrict__ Wul,
    const float* __restrict__ bg, const float* __restrict__ bu,
    const float* __restrict__ qin, float* __restrict__ qout,
    u16* __restrict__ qoh, u16* __restrict__ qol) {
    __shared__ u16 sm[24576];
    int tid = threadIdx.x;
    int w = tid >> 6, l = tid & 63, lr = l & 15, ls = l >> 4;
    int wr = w >> 1, wc = w & 1;
    int m0 = blockIdx.x * 64, n0 = blockIdx.y * 64;
    f32x4 ag[2][2], au[2][2];
#pragma unroll
    for (int i = 0; i < 2; ++i)
#pragma unroll
        for (int j = 0; j < 2; ++j) { ag[i][j] = f32x4{0.f, 0.f, 0.f, 0.f}; au[i][j] = f32x4{0.f, 0.f, 0.f, 0.f}; }

    auto stage = [&](u16* dst, int k0) {
        int q = tid, row = q >> 2, sl = q & 3;
        int kk = ((sl ^ ((row >> 1) & 3)) << 3);
        int mrow = m0 + row, nrow = n0 + row;
        const u16 *sa, *sb;
        if (k0 < 512)       { sa = fhp + (size_t)mrow * DD + k0 + kk;          sb = flp + (size_t)mrow * DD + k0 + kk; }
        else if (k0 < 1024) { sa = qhp + (size_t)mrow * DD + (k0 - 512) + kk;  sb = qlp + (size_t)mrow * DD + (k0 - 512) + kk; }
        else { int brow = mrow / CC; sa = chp + (size_t)brow * DD + (k0 - 1024) + kk; sb = clp + (size_t)brow * DD + (k0 - 1024) + kk; }
        gl_lds16(sa, dst + q * 8);
        gl_lds16(sb, dst + 2048 + q * 8);
        gl_lds16(Wgh + (size_t)nrow * 1536 + k0 + kk, dst + 4096 + q * 8);
        gl_lds16(Wgl + (size_t)nrow * 1536 + k0 + kk, dst + 6144 + q * 8);
        if (k0 < 1024) {
            gl_lds16(Wuh + (size_t)nrow * 1024 + k0 + kk, dst + 8192 + q * 8);
            gl_lds16(Wul + (size_t)nrow * 1024 + k0 + kk, dst + 10240 + q * 8);
        }
    };

    stage(sm, 0);
    __syncthreads();
    for (int t = 0; t < 48; ++t) {
        u16* cur = sm + ((t & 1) ? 12288 : 0);
        u16* nxt = sm + ((t & 1) ? 0 : 12288);
        if (t + 1 < 48) stage(nxt, (t + 1) * 32);
        bf16x8 a_h[2], a_l[2], g_h[2], g_l[2], u_h[2], u_l[2];
#pragma unroll
        for (int rf = 0; rf < 2; ++rf) {
            int arow = 32 * wr + 16 * rf + lr;
            int ao = arow * 32 + ((ls ^ ((arow >> 1) & 3)) << 3);
            a_h[rf] = *(const bf16x8*)(cur + ao);
            a_l[rf] = *(const bf16x8*)(cur + 2048 + ao);
        }
#pragma unroll
        for (int cf = 0; cf < 2; ++cf) {
            int n = 32 * wc + 16 * cf + lr;
            int no = n * 32 + ((ls ^ ((n >> 1) & 3)) << 3);
            g_h[cf] = *(const bf16x8*)(cur + 4096 + no);
            g_l[cf] = *(const bf16x8*)(cur + 6144 + no);
            if (t < 32) {
                u_h[cf] = *(const bf16x8*)(cur + 8192 + no);
                u_l[cf] = *(const bf16x8*)(cur + 10240 + no);
            }
        }
#pragma unroll
        for (int rf = 0; rf < 2; ++rf)
#pragma unroll
            for (int cf = 0; cf < 2; ++cf) {
                ag[rf][cf] = mfma16(a_h[rf], g_h[cf], ag[rf][cf]);
                ag[rf][cf] = mfma16(a_h[rf], g_l[cf], ag[rf][cf]);
                ag[rf][cf] = mfma16(a_l[rf], g_h[cf], ag[rf][cf]);
                if (t < 32) {
                    au[rf][cf] = mfma16(a_h[rf], u_h[cf], au[rf][cf]);
                    au[rf][cf] = mfma16(a_h[rf], u_l[cf], au[rf][cf]);
                    au[rf][cf] = mfma16(a_l[rf], u_h[cf], au[rf][cf]);
                }
            }
        __syncthreads();
    }
#pragma unroll
    for (int rf = 0; rf < 2; ++rf)
#pragma unroll
        for (int cf = 0; cf < 2; ++cf)
#pragma unroll
            for (int r = 0; r < 4; ++r) {
                int row = m0 + 32 * wr + 16 * rf + 4 * ls + r;
                int col = n0 + 32 * wc + 16 * cf + lr;
                float g = 1.0f / (1.0f + __expf(-(ag[rf][cf][r] + bg[col])));
                float u = tanhf(au[rf][cf][r] + bu[col]);
                size_t o = (size_t)row * DD + col;
                float qv = qin[o];
                float qo = g * qv + (1.0f - g) * u;
                qout[o] = qo;
                u16 hh = bf16h(qo);
                qoh[o] = hh;
                qol[o] = bf16h(qo - bf2f(hh));
            }
}

// ---------------------------------------------------------------------------
__global__ __launch_bounds__(256) void init_q_loss(const float* __restrict__ ce,
                                                   float* __restrict__ q0,
                                                   u16* __restrict__ qh, u16* __restrict__ ql,
                                                   float* __restrict__ loss) {
    int i = blockIdx.x * 256 + threadIdx.x;
    float v = ce[i % (CC * DD)];
    q0[i] = v;
    u16 hh = bf16h(v);
    qh[i] = hh;
    ql[i] = bf16h(v - bf2f(hh));
    if (i == 0) loss[0] = 0.0f;
}

// ---------------------------------------------------------------------------
__global__ __launch_bounds__(256) void final_kernel(const float* __restrict__ fuse_last,
                                                    const float* __restrict__ ce,
                                                    const float* __restrict__ W_cls,
                                                    const float* __restrict__ b_cls,
                                                    const float* __restrict__ loss_acc,
                                                    float* __restrict__ out) {
    int b = blockIdx.x;
    int t = threadIdx.x;
    int w = t >> 6, lane = t & 63;
    __shared__ float invn[CC];
    __shared__ float img[CC];
    const float* fb = fuse_last + (size_t)b * CC * DD;
    for (int c = w; c < CC; c += 4) {
        const float* fr = fb + (size_t)c * DD + lane * 8;
        float4 a0 = *(const float4*)fr;
        float4 a1 = *(const float4*)(fr + 4);
        float ss = a0.x * a0.x + a0.y * a0.y + a0.z * a0.z + a0.w * a0.w +
                   a1.x * a1.x + a1.y * a1.y + a1.z * a1.z + a1.w * a1.w;
#pragma unroll
        for (int off = 32; off > 0; off >>= 1) ss += __shfl_xor(ss, off);
        if (lane == 0) invn[c] = 1.0f / fmaxf(sqrtf(ss), 1e-12f);
    }
    __syncthreads();
    for (int g = w; g < CC; g += 4) {
        int k = g / 6;
        const float* ar = ce + (size_t)g * DD + lane * 8;
        float4 c0 = *(const float4*)ar;
        float4 c1 = *(const float4*)(ar + 4);
        float av[8] = {c0.x, c0.y, c0.z, c0.w, c1.x, c1.y, c1.z, c1.w};
        float accp = 0.0f;
        for (int p = 0; p < 6; ++p) {
            int row = k * 6 + p;
            const float* fr = fb + (size_t)row * DD + lane * 8;
            float4 f0 = *(const float4*)fr;
            float4 f1 = *(const float4*)(fr + 4);
            float fv[8] = {f0.x, f0.y, f0.z, f0.w, f1.x, f1.y, f1.z, f1.w};
            float d = 0.0f;
#pragma unroll
            for (int j = 0; j < 8; ++j) d += fv[j] * av[j];
            accp += d * invn[row];
        }
#pragma unroll
        for (int off = 32; off > 0; off >>= 1) accp += __shfl_xor(accp, off);
        if (lane == 0) img[g] = accp * (100.0f / 6.0f);
    }
    __syncthreads();
    if (t < CC) out[BB * 7 + b * CC + t] = img[t];
    if (t < 7) {
        float sacc = b_cls[t];
        for (int c = 0; c < CC; ++c) sacc += img[c] * W_cls[t * CC + c];
        out[b * 7 + t] = sacc;
    }
    if (b == 0 && t == 0) out[BB * 7 + BB * CC] = loss_acc[0] * (1.0f / LOSS_DEN);
}

// ---------------------------------------------------------------------------
extern "C" void kernel_launch(void* const* d_in, const int* in_sizes, int n_in,
                              void* d_out, int out_size, void* d_ws, size_t ws_size,
                              hipStream_t stream) {
    const float* feats = (const float*)d_in[0];
    const float* ce = (const float*)d_in[1];
    const float* W_lin = (const float*)d_in[2];
    const float* b_lin = (const float*)d_in[3];
    const float* W_proj = (const float*)d_in[4];
    const float* W_gate = (const float*)d_in[5];
    const float* b_gate = (const float*)d_in[6];
    const float* W_upd = (const float*)d_in[7];
    const float* b_upd = (const float*)d_in[8];
    const float* W_cls = (const float*)d_in[9];
    const float* b_cls = (const float*)d_in[10];
    float* out = (float*)d_out;

    char* base = (char*)d_ws;
    size_t off = 0;
    auto alloc = [&](size_t bytes) -> char* {
        char* r = base + off;
        off += (bytes + 255) & ~(size_t)255;
        return r;
    };
    u16* Xh = (u16*)alloc((size_t)LL * BB * VV * DV * 2);
    u16* Xl = (u16*)alloc((size_t)LL * BB * VV * DV * 2);
    u16* vth = (u16*)alloc((size_t)LL * BB * VV * DD * 2);
    u16* vtl = (u16*)alloc((size_t)LL * BB * VV * DD * 2);
    u16* vtTh = (u16*)alloc((size_t)LL * BB * 512 * 64 * 2);
    u16* vtTl = (u16*)alloc((size_t)LL * BB * 512 * 64 * 2);
    float* ctx = (float*)alloc((size_t)LL * BB * DD * 4);
    float* qbuf[2] = {(float*)alloc((size_t)BB * CC * DD * 4), (float*)alloc((size_t)BB * CC * DD * 4)};
    float* fbuf[2] = {(float*)alloc((size_t)BB * CC * DD * 4), (float*)alloc((size_t)BB * CC * DD * 4)};
    float* loss = (float*)alloc(256);
    u16* Wlh = (u16*)alloc((size_t)NL * 2);
    u16* Wll = (u16*)alloc((size_t)NL * 2);
    u16* Wgh = (u16*)alloc((size_t)NG * 2);
    u16* Wgl = (u16*)alloc((size_t)NG * 2);
    u16* Wuh = (u16*)alloc((size_t)NU * 2);
    u16* Wul = (u16*)alloc((size_t)NU * 2);
    u16* ch = (u16*)alloc((size_t)LL * BB * DD * 2);
    u16* cl = (u16*)alloc((size_t)LL * BB * DD * 2);
    u16* fh = (u16*)alloc((size_t)BB * CC * DD * 2);
    u16* fl = (u16*)alloc((size_t)BB * CC * DD * 2);
    u16* qph[2] = {(u16*)alloc((size_t)BB * CC * DD * 2), (u16*)alloc((size_t)BB * CC * DD * 2)};
    u16* qpl[2] = {(u16*)alloc((size_t)BB * CC * DD * 2), (u16*)alloc((size_t)BB * CC * DD * 2)};

    // Precompute
    pool_split<<<LL * BB * VV, 256, 0, stream>>>(feats, Xh, Xl);
    wsplit_all<<<(NL + NG + NU) / 256, 256, 0, stream>>>(W_lin, W_gate, W_upd, Wlh, Wll, Wgh, Wgl, Wuh, Wul);
    {
        dim3 g(LL * BB / 64, DD / 64);
        gemm_nt<<<g, 256, 0, stream>>>(feats, SS * DV, W_proj, DV, nullptr, ctx, ch, cl);
    }
    init_q_loss<<<(BB * CC * DD) / 256, 256, 0, stream>>>(ce, qbuf[0], qph[0], qpl[0], loss);
    {
        dim3 g(147, 8);
        vt_gemm<<<g, 256, 0, stream>>>(Xh, Xl, Wlh, Wll, b_lin, vth, vtl);
    }
    vtT_kernel<<<LL * BB, 256, 0, stream>>>(vth, vtl, vtTh, vtTl);

    int qc = 0;
    for (int l = 0; l < LL; ++l) {
        float* fcur = fbuf[l & 1];
        float* fprev = fbuf[(l & 1) ^ 1];
        attn_mfma<<<BB, 512, 0, stream>>>(qph[qc], qpl[qc],
                                          vth + (size_t)l * BB * VV * DD, vtl + (size_t)l * BB * VV * DD,
                                          vtTh + (size_t)l * BB * 512 * 64, vtTl + (size_t)l * BB * 512 * 64,
                                          fcur, fh, fl, fprev, loss, l > 0 ? 1 : 0);
        if (l < LL - 1) {
            dim3 g(BB * CC / 64, DD / 64);
            gate_upd2<<<g, 256, 0, stream>>>(fh, fl, qph[qc], qpl[qc],
                                             ch + (size_t)l * BB * DD, cl + (size_t)l * BB * DD,
                                             Wgh, Wgl, Wuh, Wul, b_gate, b_upd,
                                             qbuf[qc], qbuf[qc ^ 1], qph[qc ^ 1], qpl[qc ^ 1]);
            qc ^= 1;
        }
    }

    final_kernel<<<BB, 256, 0, stream>>>(fbuf[(LL - 1) & 1], ce, W_cls, b_cls, loss, out);
}